// Round 13
// baseline (87.522 us; speedup 1.0000x reference)
//
#include <hip/hip_runtime.h>
#include <hip/hip_bf16.h>

// Problem constants
#define Bk 8
#define Nk 10000
#define Ek 160000
#define Hk 128
#define Zk 64
#define CAPk 64      // bucket-CSR capacity; deg ~ Poisson(16), P(deg>=64) ~ 0
#define NTILES 313   // ceil(10000/32)
#define NROWS 10016  // h1/csr rows per batch (incl. zero rows; rows >= Nk are zero)

typedef float f32x4 __attribute__((ext_vector_type(4)));
typedef float f32x2 __attribute__((ext_vector_type(2)));
typedef short s16x8 __attribute__((ext_vector_type(8)));
typedef unsigned u32x4 __attribute__((ext_vector_type(4)));

__device__ inline f32x2 pk_add(f32x2 a, f32x2 b){
  f32x2 d; asm("v_pk_add_f32 %0, %1, %2" : "=v"(d) : "v"(a), "v"(b)); return d;
}
__device__ inline f32x2 bf2_to_f32x2(unsigned v){
  f32x2 r; r.x = __uint_as_float(v<<16); r.y = __uint_as_float(v & 0xffff0000u); return r;
}
__device__ inline unsigned pack_bf2(float lo, float hi){
  __hip_bfloat162 p; p.x = __float2bfloat16(lo); p.y = __float2bfloat16(hi);
  return *(unsigned*)&p;
}

// init: pack WBT (128x256 bf16: [W2l | W2r] rows), zero cur + pooled
__global__ __launch_bounds__(256) void k0_init(const float* __restrict__ W2l, const float* __restrict__ W2r,
                                               __hip_bfloat16* __restrict__ wbt, int* __restrict__ cur,
                                               float* __restrict__ pooled){
  int t = blockIdx.x*256 + threadIdx.x;
  if (t < 128*256){
    int o = t >> 8, k = t & 255;
    float v = (k < 128) ? W2l[o*128+k] : W2r[o*128+(k-128)];
    wbt[t] = __float2bfloat16(v);
  }
  if (t < Nk) cur[t] = 0;
  if (t < Bk*Hk) pooled[t] = 0.f;
}

// bucket-CSR fill: csrsrc[d*CAP + p] = src, cur[d] = degree
__global__ void k3_fill(const int* __restrict__ ei, int* __restrict__ cur, int* __restrict__ csrsrc){
  int e = blockIdx.x*blockDim.x + threadIdx.x;
  if (e < Ek){
    int s = ei[e], d = ei[Ek+e];
    int p = atomicAdd(&cur[d], 1);
    if (p < CAPk) csrsrc[d*CAPk + p] = s;
  }
}

// Fused agg1 + H1: one wave per node. Lane k gathers edge k's x (exec-masked),
// 6-shfl butterfly -> agg1 in-register -> h1 row = relu(agg1*w1l + x_i*w1r + b1)
// stored bf16. Zero rows for i in [Nk, NROWS).
__global__ __launch_bounds__(256) void k45_h1(const float* __restrict__ x, const int* __restrict__ cur,
                        const int* __restrict__ csrsrc,
                        const float* __restrict__ W1l, const float* __restrict__ b1,
                        const float* __restrict__ W1r, __hip_bfloat16* __restrict__ h1){
  int i = blockIdx.x*4 + (threadIdx.x>>6);
  int lane = threadIdx.x & 63;
  if (i >= Nk){
    if (i < NROWS){
      #pragma unroll
      for (int b=0;b<Bk;b++)
        *(unsigned*)((void*)(h1 + ((size_t)b*NROWS + i)*128 + 2*lane)) = 0u;
    }
    return;
  }
  float2 wl = *(const float2*)(W1l + 2*lane);
  float2 wr = *(const float2*)(W1r + 2*lane);
  float2 bb = *(const float2*)(b1  + 2*lane);
  int degc = cur[i];
  int deg = min(degc, CAPk);
  const int* col = csrsrc + (size_t)i*CAPk;
  int j = 0;
  bool havej = (lane < deg);
  if (havej) j = col[lane];
  float inv = 1.f/fmaxf((float)degc, 1.f);

  float xx[Bk];
  #pragma unroll
  for (int b=0;b<Bk;b++){
    float v = 0.f;
    if (havej) v = x[b*Nk + j];
    xx[b] = v;
  }
  #pragma unroll
  for (int b=0;b<Bk;b++){
    float s = xx[b];
    s += __shfl_xor(s, 1);  s += __shfl_xor(s, 2);  s += __shfl_xor(s, 4);
    s += __shfl_xor(s, 8);  s += __shfl_xor(s, 16); s += __shfl_xor(s, 32);
    float a  = s * inv;
    float xi = x[b*Nk + i];
    float v0 = fmaxf(fmaf(a, wl.x, fmaf(xi, wr.x, bb.x)), 0.f);
    float v1 = fmaxf(fmaf(a, wl.y, fmaf(xi, wr.y, bb.y)), 0.f);
    *(unsigned*)((void*)(h1 + ((size_t)b*NROWS + i)*128 + 2*lane)) = pack_bf2(v0, v1);
  }
}

__device__ inline void mfma_bf16(f32x4& d, s16x8 a, s16x8 b){
  asm("v_mfma_f32_16x16x32_bf16 %0, %1, %2, %0" : "+v"(d) : "v"(a), "v"(b));
}

// Fused layer-2: csr tile in LDS (per-slot pad-patch -> zero row Nk), agg2
// gather with DUAL-ROW interleave: each 16-lane group owns rows rgA, rgB;
// one loop, two wave-uniform guards, 8 independent dwordx4 row-loads in
// flight per wave. 32-bit voffsets (slice = 2.56 MB). Then LDS A-tile
// [agg2|h1] -> MFMA -> relu+bias -> column-sum -> atomic pooled.
// batch = blockIdx.x == XCD -> per-XCD L2-resident h1.
__global__ __launch_bounds__(256) void kB_fused(const __hip_bfloat16* __restrict__ h1,
                        const int* __restrict__ cur, const int* __restrict__ csrsrc,
                        const __hip_bfloat16* __restrict__ wbt, const float* __restrict__ b2,
                        float* __restrict__ pooled){
  __shared__ char At[32*512];        // 32 rows x 256 bf16, XOR-swizzled
  __shared__ int scol[32*CAPk];      // 8 KB csr tile (pad-patched)
  __shared__ int sdeg[32];
  int b = blockIdx.x, tile = blockIdx.y;
  int tid = threadIdx.x;
  int wid = tid >> 6, lane = tid & 63;
  int g = lane >> 4, l4 = lane & 15;
  const char* h1b = (const char*)(h1 + (size_t)b*NROWS*128);
  unsigned loff = (unsigned)(l4*16);

  if (tid < 32){
    int i = tile*32 + tid;
    sdeg[tid] = (i < Nk) ? cur[i] : 0;
  }
  __syncthreads();

  // stage csr tile (nontemporal), per-slot patch: slot >= deg(row) -> Nk
  {
    const u32x4* src = (const u32x4*)(csrsrc + (size_t)tile*32*CAPk);
    u32x4* dst = (u32x4*)scol;
    #pragma unroll
    for (int h=0; h<2; ++h){
      int idx = h*256 + tid;
      u32x4 v = __builtin_nontemporal_load(src + idx);
      int row = idx >> 4;            // 16 quads per row
      int p = (idx & 15) * 4;        // slot within row (multiple of 4)
      int d = min(sdeg[row], CAPk);
      if (p+0 >= d) v.x = Nk;
      if (p+1 >= d) v.y = Nk;
      if (p+2 >= d) v.z = Nk;
      if (p+3 >= d) v.w = Nk;
      dst[idx] = v;
    }
  }
  __syncthreads();

  // phase 1: group g owns rows rgA = wid*8+g, rgB = wid*8+4+g (two streams)
  {
    int rgA = wid*8 + g,     rgB = wid*8 + 4 + g;
    int igA = tile*32 + rgA, igB = tile*32 + rgB;
    int dcA = sdeg[rgA],     dcB = sdeg[rgB];
    int kmA = (min(dcA, CAPk) + 3) & ~3;
    kmA = max(kmA, __shfl_xor(kmA, 16));
    kmA = max(kmA, __shfl_xor(kmA, 32));   // wave-uniform
    int kmB = (min(dcB, CAPk) + 3) & ~3;
    kmB = max(kmB, __shfl_xor(kmB, 16));
    kmB = max(kmB, __shfl_xor(kmB, 32));   // wave-uniform

    // self rows early (always valid: zero rows beyond Nk)
    u32x4 svA = *(const u32x4*)(h1b + (unsigned)(igA*256) + loff);
    u32x4 svB = *(const u32x4*)(h1b + (unsigned)(igB*256) + loff);

    f32x2 aA0={0.f,0.f}, aA1={0.f,0.f}, aA2={0.f,0.f}, aA3={0.f,0.f};
    f32x2 aB0={0.f,0.f}, aB1={0.f,0.f}, aB2={0.f,0.f}, aB3={0.f,0.f};
    const int* colA = scol + rgA*CAPk;
    const int* colB = scol + rgB*CAPk;
    int km = max(kmA, kmB);
    for (int k=0; k<km; k+=4){
      if (k < kmA){
        int4 js = *(const int4*)(colA + k);          // ds_read_b128: 4 j's
        u32x4 v0 = *(const u32x4*)(h1b + (unsigned)(js.x*256) + loff);
        u32x4 v1 = *(const u32x4*)(h1b + (unsigned)(js.y*256) + loff);
        u32x4 v2 = *(const u32x4*)(h1b + (unsigned)(js.z*256) + loff);
        u32x4 v3 = *(const u32x4*)(h1b + (unsigned)(js.w*256) + loff);
        aA0 = pk_add(aA0, bf2_to_f32x2(v0.x)); aA1 = pk_add(aA1, bf2_to_f32x2(v0.y));
        aA2 = pk_add(aA2, bf2_to_f32x2(v0.z)); aA3 = pk_add(aA3, bf2_to_f32x2(v0.w));
        aA0 = pk_add(aA0, bf2_to_f32x2(v1.x)); aA1 = pk_add(aA1, bf2_to_f32x2(v1.y));
        aA2 = pk_add(aA2, bf2_to_f32x2(v1.z)); aA3 = pk_add(aA3, bf2_to_f32x2(v1.w));
        aA0 = pk_add(aA0, bf2_to_f32x2(v2.x)); aA1 = pk_add(aA1, bf2_to_f32x2(v2.y));
        aA2 = pk_add(aA2, bf2_to_f32x2(v2.z)); aA3 = pk_add(aA3, bf2_to_f32x2(v2.w));
        aA0 = pk_add(aA0, bf2_to_f32x2(v3.x)); aA1 = pk_add(aA1, bf2_to_f32x2(v3.y));
        aA2 = pk_add(aA2, bf2_to_f32x2(v3.z)); aA3 = pk_add(aA3, bf2_to_f32x2(v3.w));
      }
      if (k < kmB){
        int4 js = *(const int4*)(colB + k);
        u32x4 v0 = *(const u32x4*)(h1b + (unsigned)(js.x*256) + loff);
        u32x4 v1 = *(const u32x4*)(h1b + (unsigned)(js.y*256) + loff);
        u32x4 v2 = *(const u32x4*)(h1b + (unsigned)(js.z*256) + loff);
        u32x4 v3 = *(const u32x4*)(h1b + (unsigned)(js.w*256) + loff);
        aB0 = pk_add(aB0, bf2_to_f32x2(v0.x)); aB1 = pk_add(aB1, bf2_to_f32x2(v0.y));
        aB2 = pk_add(aB2, bf2_to_f32x2(v0.z)); aB3 = pk_add(aB3, bf2_to_f32x2(v0.w));
        aB0 = pk_add(aB0, bf2_to_f32x2(v1.x)); aB1 = pk_add(aB1, bf2_to_f32x2(v1.y));
        aB2 = pk_add(aB2, bf2_to_f32x2(v1.z)); aB3 = pk_add(aB3, bf2_to_f32x2(v1.w));
        aB0 = pk_add(aB0, bf2_to_f32x2(v2.x)); aB1 = pk_add(aB1, bf2_to_f32x2(v2.y));
        aB2 = pk_add(aB2, bf2_to_f32x2(v2.z)); aB3 = pk_add(aB3, bf2_to_f32x2(v2.w));
        aB0 = pk_add(aB0, bf2_to_f32x2(v3.x)); aB1 = pk_add(aB1, bf2_to_f32x2(v3.y));
        aB2 = pk_add(aB2, bf2_to_f32x2(v3.z)); aB3 = pk_add(aB3, bf2_to_f32x2(v3.w));
      }
    }
    float invA = 1.f/fmaxf((float)dcA, 1.f);
    float invB = 1.f/fmaxf((float)dcB, 1.f);
    unsigned swzA = (unsigned)((rgA & 7) << 4);
    unsigned swzB = (unsigned)((rgB & 7) << 4);
    u32x4 oA, oB;
    oA.x = pack_bf2(aA0.x*invA, aA0.y*invA);
    oA.y = pack_bf2(aA1.x*invA, aA1.y*invA);
    oA.z = pack_bf2(aA2.x*invA, aA2.y*invA);
    oA.w = pack_bf2(aA3.x*invA, aA3.y*invA);
    oB.x = pack_bf2(aB0.x*invB, aB0.y*invB);
    oB.y = pack_bf2(aB1.x*invB, aB1.y*invB);
    oB.z = pack_bf2(aB2.x*invB, aB2.y*invB);
    oB.w = pack_bf2(aB3.x*invB, aB3.y*invB);
    *(u32x4*)(At + rgA*512 + ((unsigned)(l4*16) ^ swzA))       = oA;
    *(u32x4*)(At + rgA*512 + ((unsigned)(256 + l4*16) ^ swzA)) = svA;
    *(u32x4*)(At + rgB*512 + ((unsigned)(l4*16) ^ swzB))       = oB;
    *(u32x4*)(At + rgB*512 + ((unsigned)(256 + l4*16) ^ swzB)) = svB;
  }
  __syncthreads();

  // phase 2: GEMM 32x256 @ 256x128; wave w -> cols 32w..32w+31
  int lr = lane & 15, lk = lane >> 4;
  f32x4 acc[2][2];
  #pragma unroll
  for (int mf=0; mf<2; ++mf)
    #pragma unroll
    for (int q=0; q<2; ++q) acc[mf][q] = (f32x4){0.f,0.f,0.f,0.f};

  unsigned rsw = (unsigned)((lr & 7) << 4);
  #pragma unroll
  for (int kk=0; kk<8; ++kk){
    unsigned cb = kk*64 + lk*16;
    s16x8 a0 = *(const s16x8*)(At + lr*512      + (cb ^ rsw));
    s16x8 a1 = *(const s16x8*)(At + (16+lr)*512 + (cb ^ rsw));
    #pragma unroll
    for (int q=0; q<2; ++q){
      int nf = wid*2 + q;
      s16x8 bfr = *(const s16x8*)(const void*)(wbt + (nf*16+lr)*256 + kk*32 + lk*8);
      mfma_bf16(acc[0][q], a0, bfr);
      mfma_bf16(acc[1][q], a1, bfr);
    }
  }

  // epilogue: relu(acc + b2), mask pad rows, column-reduce, atomic into pooled
  #pragma unroll
  for (int q=0; q<2; ++q){
    int colc = (wid*2+q)*16 + lr;
    float bias = b2[colc];
    float v = 0.f;
    #pragma unroll
    for (int mf=0; mf<2; ++mf){
      int rbase = tile*32 + mf*16 + lk*4;
      #pragma unroll
      for (int r=0;r<4;++r){
        float val = fmaxf(acc[mf][q][r] + bias, 0.f);
        if (rbase + r < Nk) v += val;
      }
    }
    v += __shfl_xor(v, 16);
    v += __shfl_xor(v, 32);
    if (lane < 16) atomicAdd(&pooled[b*Hk + colc], v);
  }
}

__global__ void k7_final(const float* __restrict__ pooled, const float* __restrict__ Wro1,
                         const float* __restrict__ bro1, const float* __restrict__ Wro2,
                         const float* __restrict__ bro2, float* __restrict__ out){
  int b = blockIdx.x, t = threadIdx.x;
  __shared__ float pool[128];
  __shared__ float hid[128];
  pool[t] = pooled[b*Hk + t] * (1.0f/(float)Nk);
  __syncthreads();
  float s = bro1[t];
  for (int d=0; d<128; ++d) s += Wro1[t*128+d]*pool[d];
  hid[t] = fmaxf(s, 0.f);
  __syncthreads();
  if (t < Zk){
    float s2 = bro2[t];
    for (int d=0; d<128; ++d) s2 += Wro2[t*128+d]*hid[d];
    out[b*Zk + t] = s2;
  }
}

extern "C" void kernel_launch(void* const* d_in, const int* in_sizes, int n_in,
                              void* d_out, int out_size, void* d_ws, size_t ws_size,
                              hipStream_t stream) {
  const float* x    = (const float*)d_in[0];
  const int*   ei   = (const int*)d_in[1];
  const float* W1l  = (const float*)d_in[2];
  const float* b1   = (const float*)d_in[3];
  const float* W1r  = (const float*)d_in[4];
  const float* W2l  = (const float*)d_in[5];
  const float* b2   = (const float*)d_in[6];
  const float* W2r  = (const float*)d_in[7];
  const float* Wro1 = (const float*)d_in[8];
  const float* bro1 = (const float*)d_in[9];
  const float* Wro2 = (const float*)d_in[10];
  const float* bro2 = (const float*)d_in[11];
  float* out = (float*)d_out;

  // workspace layout (bytes, 256-aligned)
  char* ws = (char*)d_ws;
  int*   cur    = (int*)(ws + 0);              // 40000
  float* pooled = (float*)(ws + 40448);        // 4096
  __hip_bfloat16* wbt = (__hip_bfloat16*)(ws + 44544);    // 65536
  int*   csrsrc = (int*)(ws + 110080);         // 10016*64*4 = 2564096
  __hip_bfloat16* h1 = (__hip_bfloat16*)(ws + 2674176);   // 8*10016*128*2 = 20512768

  k0_init<<<dim3(128), 256, 0, stream>>>(W2l, W2r, wbt, cur, pooled);
  k3_fill<<<dim3((Ek+255)/256), 256, 0, stream>>>(ei, cur, csrsrc);
  k45_h1<<<dim3(2504), 256, 0, stream>>>(x, cur, csrsrc, W1l, b1, W1r, h1);
  kB_fused<<<dim3(Bk, NTILES), 256, 0, stream>>>(h1, cur, csrsrc, wbt, b2, pooled);
  k7_final<<<dim3(Bk), 128, 0, stream>>>(pooled, Wro1, bro1, Wro2, bro2, out);
}

// Round 14
// 87.075 us; speedup vs baseline: 1.0051x; 1.0051x over previous
//
#include <hip/hip_runtime.h>
#include <hip/hip_bf16.h>

// Problem constants
#define Bk 8
#define Nk 10000
#define Ek 160000
#define Hk 128
#define Zk 64
#define CAPk 64      // bucket-CSR capacity; deg ~ Poisson(16), P(deg>=64) ~ 0
#define NTILES 313   // ceil(10000/32)
#define NROWS 10016  // h1/csr rows per batch (rows >= Nk are zero; row Nk = pad target)

typedef float f32x4 __attribute__((ext_vector_type(4)));
typedef float f32x2 __attribute__((ext_vector_type(2)));
typedef short s16x8 __attribute__((ext_vector_type(8)));
typedef unsigned u32x4 __attribute__((ext_vector_type(4)));

__device__ inline f32x2 pk_add(f32x2 a, f32x2 b){
  f32x2 d; asm("v_pk_add_f32 %0, %1, %2" : "=v"(d) : "v"(a), "v"(b)); return d;
}
__device__ inline f32x2 bf2_to_f32x2(unsigned v){
  f32x2 r; r.x = __uint_as_float(v<<16); r.y = __uint_as_float(v & 0xffff0000u); return r;
}
__device__ inline unsigned pack_bf2(float lo, float hi){
  __hip_bfloat162 p; p.x = __float2bfloat16(lo); p.y = __float2bfloat16(hi);
  return *(unsigned*)&p;
}

// init: pack WBT, zero cur+pooled, fill ALL csrsrc slots with Nk (zero-row pad).
// grid 2504*256 = 641024 == NROWS*CAPk exactly.
__global__ __launch_bounds__(256) void k0_init(const float* __restrict__ W2l, const float* __restrict__ W2r,
                                               __hip_bfloat16* __restrict__ wbt, int* __restrict__ cur,
                                               float* __restrict__ pooled, int* __restrict__ csrsrc){
  int t = blockIdx.x*256 + threadIdx.x;
  if (t < 128*256){
    int o = t >> 8, k = t & 255;
    float v = (k < 128) ? W2l[o*128+k] : W2r[o*128+(k-128)];
    wbt[t] = __float2bfloat16(v);
  }
  if (t < Nk) cur[t] = 0;
  if (t < Bk*Hk) pooled[t] = 0.f;
  csrsrc[t] = Nk;   // t < NROWS*CAPk by construction
}

// bucket-CSR fill: csrsrc[d*CAP + p] = src, cur[d] = degree
__global__ void k3_fill(const int* __restrict__ ei, int* __restrict__ cur, int* __restrict__ csrsrc){
  int e = blockIdx.x*blockDim.x + threadIdx.x;
  if (e < Ek){
    int s = ei[e], d = ei[Ek+e];
    int p = atomicAdd(&cur[d], 1);
    if (p < CAPk) csrsrc[d*CAPk + p] = s;
  }
}

// Fused agg1 + H1: one wave per node. Lane k gathers edge k's x (exec-masked),
// 6-shfl butterfly -> agg1 in-register -> h1 row = relu(agg1*w1l + x_i*w1r + b1)
// stored bf16. Zero rows for i in [Nk, NROWS).
__global__ __launch_bounds__(256) void k45_h1(const float* __restrict__ x, const int* __restrict__ cur,
                        const int* __restrict__ csrsrc,
                        const float* __restrict__ W1l, const float* __restrict__ b1,
                        const float* __restrict__ W1r, __hip_bfloat16* __restrict__ h1){
  int i = blockIdx.x*4 + (threadIdx.x>>6);
  int lane = threadIdx.x & 63;
  if (i >= Nk){
    if (i < NROWS){
      #pragma unroll
      for (int b=0;b<Bk;b++)
        *(unsigned*)((void*)(h1 + ((size_t)b*NROWS + i)*128 + 2*lane)) = 0u;
    }
    return;
  }
  float2 wl = *(const float2*)(W1l + 2*lane);
  float2 wr = *(const float2*)(W1r + 2*lane);
  float2 bb = *(const float2*)(b1  + 2*lane);
  int degc = cur[i];
  int deg = min(degc, CAPk);
  const int* col = csrsrc + (size_t)i*CAPk;
  int j = 0;
  bool havej = (lane < deg);
  if (havej) j = col[lane];
  float inv = 1.f/fmaxf((float)degc, 1.f);

  float xx[Bk];
  #pragma unroll
  for (int b=0;b<Bk;b++){
    float v = 0.f;
    if (havej) v = x[b*Nk + j];
    xx[b] = v;
  }
  #pragma unroll
  for (int b=0;b<Bk;b++){
    float s = xx[b];
    s += __shfl_xor(s, 1);  s += __shfl_xor(s, 2);  s += __shfl_xor(s, 4);
    s += __shfl_xor(s, 8);  s += __shfl_xor(s, 16); s += __shfl_xor(s, 32);
    float a  = s * inv;
    float xi = x[b*Nk + i];
    float v0 = fmaxf(fmaf(a, wl.x, fmaf(xi, wr.x, bb.x)), 0.f);
    float v1 = fmaxf(fmaf(a, wl.y, fmaf(xi, wr.y, bb.y)), 0.f);
    *(unsigned*)((void*)(h1 + ((size_t)b*NROWS + i)*128 + 2*lane)) = pack_bf2(v0, v1);
  }
}

__device__ inline void mfma_bf16(f32x4& d, s16x8 a, s16x8 b){
  asm("v_mfma_f32_16x16x32_bf16 %0, %1, %2, %0" : "+v"(d) : "v"(a), "v"(b));
}

// Fused layer-2, occupancy-tuned: NO csr LDS staging (csrsrc pre-padded with
// Nk in k0, read direct from global — L2-resident, group-uniform addr ->
// L1 broadcast). LDS = At (16 KB) + sdeg -> 8 blocks/CU = 32 waves (vs 14).
// Gather: group-owns-row quad loop, 4 independent dwordx4 row-loads per step,
// pads hit the zero row. Then LDS A-tile [agg2|h1] -> MFMA -> relu+bias ->
// column-sum -> atomic pooled. batch = blockIdx.x == XCD.
__global__ __launch_bounds__(256) void kB_fused(const __hip_bfloat16* __restrict__ h1,
                        const int* __restrict__ cur, const int* __restrict__ csrsrc,
                        const __hip_bfloat16* __restrict__ wbt, const float* __restrict__ b2,
                        float* __restrict__ pooled){
  __shared__ char At[32*512];        // 32 rows x 256 bf16, XOR-swizzled
  __shared__ int sdeg[32];
  int b = blockIdx.x, tile = blockIdx.y;
  int tid = threadIdx.x;
  int wid = tid >> 6, lane = tid & 63;
  int g = lane >> 4, l4 = lane & 15;
  const char* h1b = (const char*)(h1 + (size_t)b*NROWS*128);
  unsigned loff = (unsigned)(l4*16);

  if (tid < 32){
    int i = tile*32 + tid;
    sdeg[tid] = (i < Nk) ? cur[i] : 0;
  }
  __syncthreads();

  // phase 1: group g owns rows wid*8 + c*4 + g (c = 0,1)
  #pragma unroll
  for (int c=0;c<2;c++){
    int rg = wid*8 + c*4 + g;
    int ig = tile*32 + rg;
    int dc = sdeg[rg];
    int d4 = (min(dc, CAPk) + 3) & ~3;
    int km = d4;
    km = max(km, __shfl_xor(km, 16));
    km = max(km, __shfl_xor(km, 32));   // wave-uniform trip count

    // self row early (always valid: zero rows beyond Nk)
    u32x4 sv = *(const u32x4*)(h1b + (unsigned)(ig*256) + loff);

    f32x2 a0={0.f,0.f}, a1={0.f,0.f}, a2={0.f,0.f}, a3={0.f,0.f};
    const int* colg = csrsrc + ig*CAPk;   // global; slots >= deg hold Nk
    for (int k=0; k<km; k+=4){
      int4 js = *(const int4*)(colg + k);          // 16B group-uniform load
      u32x4 v0 = *(const u32x4*)(h1b + (unsigned)(js.x*256) + loff);
      u32x4 v1 = *(const u32x4*)(h1b + (unsigned)(js.y*256) + loff);
      u32x4 v2 = *(const u32x4*)(h1b + (unsigned)(js.z*256) + loff);
      u32x4 v3 = *(const u32x4*)(h1b + (unsigned)(js.w*256) + loff);
      a0 = pk_add(a0, bf2_to_f32x2(v0.x)); a1 = pk_add(a1, bf2_to_f32x2(v0.y));
      a2 = pk_add(a2, bf2_to_f32x2(v0.z)); a3 = pk_add(a3, bf2_to_f32x2(v0.w));
      a0 = pk_add(a0, bf2_to_f32x2(v1.x)); a1 = pk_add(a1, bf2_to_f32x2(v1.y));
      a2 = pk_add(a2, bf2_to_f32x2(v1.z)); a3 = pk_add(a3, bf2_to_f32x2(v1.w));
      a0 = pk_add(a0, bf2_to_f32x2(v2.x)); a1 = pk_add(a1, bf2_to_f32x2(v2.y));
      a2 = pk_add(a2, bf2_to_f32x2(v2.z)); a3 = pk_add(a3, bf2_to_f32x2(v2.w));
      a0 = pk_add(a0, bf2_to_f32x2(v3.x)); a1 = pk_add(a1, bf2_to_f32x2(v3.y));
      a2 = pk_add(a2, bf2_to_f32x2(v3.z)); a3 = pk_add(a3, bf2_to_f32x2(v3.w));
    }
    float inv = 1.f/fmaxf((float)dc, 1.f);
    u32x4 outv;
    outv.x = pack_bf2(a0.x*inv, a0.y*inv);
    outv.y = pack_bf2(a1.x*inv, a1.y*inv);
    outv.z = pack_bf2(a2.x*inv, a2.y*inv);
    outv.w = pack_bf2(a3.x*inv, a3.y*inv);
    unsigned swz = (unsigned)((rg & 7) << 4);
    *(u32x4*)(At + rg*512 + ((unsigned)(l4*16) ^ swz))       = outv;
    *(u32x4*)(At + rg*512 + ((unsigned)(256 + l4*16) ^ swz)) = sv;
  }
  __syncthreads();

  // phase 2: GEMM 32x256 @ 256x128; wave w -> cols 32w..32w+31
  int lr = lane & 15, lk = lane >> 4;
  f32x4 acc[2][2];
  #pragma unroll
  for (int mf=0; mf<2; ++mf)
    #pragma unroll
    for (int q=0; q<2; ++q) acc[mf][q] = (f32x4){0.f,0.f,0.f,0.f};

  unsigned rsw = (unsigned)((lr & 7) << 4);
  #pragma unroll
  for (int kk=0; kk<8; ++kk){
    unsigned cb = kk*64 + lk*16;
    s16x8 a0 = *(const s16x8*)(At + lr*512      + (cb ^ rsw));
    s16x8 a1 = *(const s16x8*)(At + (16+lr)*512 + (cb ^ rsw));
    #pragma unroll
    for (int q=0; q<2; ++q){
      int nf = wid*2 + q;
      s16x8 bfr = *(const s16x8*)(const void*)(wbt + (nf*16+lr)*256 + kk*32 + lk*8);
      mfma_bf16(acc[0][q], a0, bfr);
      mfma_bf16(acc[1][q], a1, bfr);
    }
  }

  // epilogue: relu(acc + b2), mask pad rows, column-reduce, atomic into pooled
  #pragma unroll
  for (int q=0; q<2; ++q){
    int colc = (wid*2+q)*16 + lr;
    float bias = b2[colc];
    float v = 0.f;
    #pragma unroll
    for (int mf=0; mf<2; ++mf){
      int rbase = tile*32 + mf*16 + lk*4;
      #pragma unroll
      for (int r=0;r<4;++r){
        float val = fmaxf(acc[mf][q][r] + bias, 0.f);
        if (rbase + r < Nk) v += val;
      }
    }
    v += __shfl_xor(v, 16);
    v += __shfl_xor(v, 32);
    if (lane < 16) atomicAdd(&pooled[b*Hk + colc], v);
  }
}

__global__ void k7_final(const float* __restrict__ pooled, const float* __restrict__ Wro1,
                         const float* __restrict__ bro1, const float* __restrict__ Wro2,
                         const float* __restrict__ bro2, float* __restrict__ out){
  int b = blockIdx.x, t = threadIdx.x;
  __shared__ float pool[128];
  __shared__ float hid[128];
  pool[t] = pooled[b*Hk + t] * (1.0f/(float)Nk);
  __syncthreads();
  float s = bro1[t];
  for (int d=0; d<128; ++d) s += Wro1[t*128+d]*pool[d];
  hid[t] = fmaxf(s, 0.f);
  __syncthreads();
  if (t < Zk){
    float s2 = bro2[t];
    for (int d=0; d<128; ++d) s2 += Wro2[t*128+d]*hid[d];
    out[b*Zk + t] = s2;
  }
}

extern "C" void kernel_launch(void* const* d_in, const int* in_sizes, int n_in,
                              void* d_out, int out_size, void* d_ws, size_t ws_size,
                              hipStream_t stream) {
  const float* x    = (const float*)d_in[0];
  const int*   ei   = (const int*)d_in[1];
  const float* W1l  = (const float*)d_in[2];
  const float* b1   = (const float*)d_in[3];
  const float* W1r  = (const float*)d_in[4];
  const float* W2l  = (const float*)d_in[5];
  const float* b2   = (const float*)d_in[6];
  const float* W2r  = (const float*)d_in[7];
  const float* Wro1 = (const float*)d_in[8];
  const float* bro1 = (const float*)d_in[9];
  const float* Wro2 = (const float*)d_in[10];
  const float* bro2 = (const float*)d_in[11];
  float* out = (float*)d_out;

  // workspace layout (bytes, 256-aligned)
  char* ws = (char*)d_ws;
  int*   cur    = (int*)(ws + 0);              // 40000
  float* pooled = (float*)(ws + 40448);        // 4096
  __hip_bfloat16* wbt = (__hip_bfloat16*)(ws + 44544);    // 65536
  int*   csrsrc = (int*)(ws + 110080);         // 10016*64*4 = 2564096
  __hip_bfloat16* h1 = (__hip_bfloat16*)(ws + 2674176);   // 8*10016*128*2 = 20512768

  k0_init<<<dim3(2504), 256, 0, stream>>>(W2l, W2r, wbt, cur, pooled, csrsrc);
  k3_fill<<<dim3((Ek+255)/256), 256, 0, stream>>>(ei, cur, csrsrc);
  k45_h1<<<dim3(2504), 256, 0, stream>>>(x, cur, csrsrc, W1l, b1, W1r, h1);
  kB_fused<<<dim3(Bk, NTILES), 256, 0, stream>>>(h1, cur, csrsrc, wbt, b2, pooled);
  k7_final<<<dim3(Bk), 128, 0, stream>>>(pooled, Wro1, bro1, Wro2, bro2, out);
}